// Round 9
// baseline (2661.316 us; speedup 1.0000x reference)
//
#include <hip/hip_runtime.h>
#include <hip/hip_bf16.h>

#define B   64
#define T   512
#define DIN 64
#define F   64
#define U   128
#define G3  384     // 3U
#define M2  256     // 2U
#define NH  4
#define KD  128
#define HD  512     // NH*KD
#define BT  (B*T)   // 32768

typedef __attribute__((ext_vector_type(8))) short short8;
typedef __attribute__((ext_vector_type(4))) float floatx4;
typedef __attribute__((ext_vector_type(4))) unsigned short ushort4_t;
typedef __hip_bfloat16 bf16;

// ---------------- weight transpose + cast: dst[n][k] = (bf16)src[k][n] ----------------
__global__ __launch_bounds__(256) void k_wcast(const float* __restrict__ src,
        bf16* __restrict__ dst, int K, int N)
{
    const int i = blockIdx.x*256 + threadIdx.x;
    if (i < K*N) {
        const int k = i / N, n = i - k*N;
        dst[n*K + k] = __float2bfloat16(src[i]);
    }
}

// ---------------- conv1d(same,k=3) + BN(inference) + ReLU -> bf16 ----------------
__global__ __launch_bounds__(256) void k_conv(const float* __restrict__ in,
        const float* __restrict__ cw, const float* __restrict__ cb,
        const float* __restrict__ gamma, const float* __restrict__ beta,
        const float* __restrict__ mean, const float* __restrict__ var,
        bf16* __restrict__ x1h)
{
    __shared__ float w_s[3*64*64];   // 48 KB
    __shared__ float in_s[18*64];
    const int b  = blockIdx.y;
    const int t0 = blockIdx.x * 16;
    const int tid = threadIdx.x;
    for (int idx = tid; idx < 3*64*64; idx += 256) w_s[idx] = cw[idx];
    for (int idx = tid; idx < 18*64; idx += 256) {
        int row = idx >> 6;
        int d   = idx & 63;
        int t   = t0 - 1 + row;
        in_s[idx] = (t >= 0 && t < T) ? in[((size_t)b*T + t)*DIN + d] : 0.0f;
    }
    __syncthreads();
    const int f  = tid & 63;
    const int tl = tid >> 6;   // 0..3
    const float scale = gamma[f] * rsqrtf(var[f] + 1e-3f);
    const float shift = beta[f] - mean[f] * scale;
    const float bias  = cb[f];
    for (int q = 0; q < 4; ++q) {
        const int tt = tl*4 + q;   // 0..15
        float acc = bias;
        for (int tap = 0; tap < 3; ++tap) {
            const float* irow = &in_s[(tt + tap)*64];
            const float* wrow = &w_s[tap*64*64 + f];
            #pragma unroll 16
            for (int d = 0; d < 64; ++d) acc += irow[d] * wrow[d*64];
        }
        float v = acc * scale + shift;
        x1h[((size_t)b*T + t0 + tt)*F + f] = __float2bfloat16(fmaxf(v, 0.0f));
    }
}

// ------------- MFMA bf16 GEMM: C[R,N] = A[R,K] @ Bt[N,K]^T + bias (+resid) -------------
__global__ __launch_bounds__(256) void k_gemm(const bf16* __restrict__ A,
        const bf16* __restrict__ Bt, const float* __restrict__ bias,
        const bf16* __restrict__ resid, float* __restrict__ outF,
        bf16* __restrict__ outH, int K, int N, int biasRow)
{
    __shared__ short As[128*32];   // 8 KB
    __shared__ short Bs[128*32];   // 8 KB
    const int nbase = blockIdx.x * 128;
    const int rbase = blockIdx.y * 128;
    const int tid  = threadIdx.x;
    const int lane = tid & 63;
    const int wv   = tid >> 6;
    const int wm   = wv & 1;        // row half
    const int wn   = wv >> 1;       // col half
    const int l16  = lane & 15;
    const int quad = lane >> 4;

    floatx4 acc[4][4];
    #pragma unroll
    for (int i = 0; i < 4; ++i)
        #pragma unroll
        for (int j = 0; j < 4; ++j) acc[i][j] = (floatx4)0.0f;

    const int row  = tid >> 1;           // staging: 2 threads per tile-row
    const int koff = (tid & 1) * 16;     // 16 bf16 = 32 B per thread
    const int nK = K >> 5;
    for (int kt = 0; kt < nK; ++kt) {
        if (kt) __syncthreads();
        {
            const float4* ga = reinterpret_cast<const float4*>(
                &A[(size_t)(rbase + row)*K + kt*32 + koff]);
            const float4 a0 = ga[0], a1 = ga[1];
            const float4* gb = reinterpret_cast<const float4*>(
                &Bt[(size_t)(nbase + row)*K + kt*32 + koff]);
            const float4 b0 = gb[0], b1 = gb[1];
            float4* la = reinterpret_cast<float4*>(&As[row*32 + koff]);
            la[0] = a0; la[1] = a1;
            float4* lb = reinterpret_cast<float4*>(&Bs[row*32 + koff]);
            lb[0] = b0; lb[1] = b1;
        }
        __syncthreads();
        short8 af[4], bf[4];
        #pragma unroll
        for (int i = 0; i < 4; ++i)
            af[i] = *reinterpret_cast<const short8*>(&As[(wm*64 + i*16 + l16)*32 + quad*8]);
        #pragma unroll
        for (int j = 0; j < 4; ++j)
            bf[j] = *reinterpret_cast<const short8*>(&Bs[(wn*64 + j*16 + l16)*32 + quad*8]);
        #pragma unroll
        for (int i = 0; i < 4; ++i)
            #pragma unroll
            for (int j = 0; j < 4; ++j)
                acc[i][j] = __builtin_amdgcn_mfma_f32_16x16x32_bf16(af[i], bf[j], acc[i][j], 0, 0, 0);
    }

    #pragma unroll
    for (int j = 0; j < 4; ++j) {
        const int gcol = nbase + wn*64 + j*16 + l16;
        const float bj = biasRow ? 0.0f : bias[gcol];
        #pragma unroll
        for (int i = 0; i < 4; ++i) {
            #pragma unroll
            for (int r = 0; r < 4; ++r) {
                const int grow = rbase + wm*64 + i*16 + quad*4 + r;
                const size_t off = (size_t)grow*N + gcol;
                float v = acc[i][j][r] + (biasRow ? bias[grow] : bj);
                if (resid) v += __bfloat162float(resid[off]);
                if (outF) outF[off] = v;
                if (outH) outH[off] = __float2bfloat16(v);
            }
        }
    }
}

// ---------------- MFMA-batched GRU scan (transposed, 2 groups/block) ----------------
__device__ __forceinline__ float sigmoidf_(float x){ return 1.0f/(1.0f + __expf(-x)); }
__device__ __forceinline__ float tanhf_(float x){ return 2.0f/(1.0f + __expf(-2.0f*x)) - 1.0f; }
__device__ __forceinline__ float bfbits2f(unsigned short u){
    return __uint_as_float(((unsigned)u) << 16);
}

// Block = 32 batches (2 independent 16-batch groups) x 1 dir; grid (2,2); 512 thr.
// hg^T = W^T(A,regs) . H^T(B,LDS). Wave wv owns gate cols wv*16..+15 (x3 gates).
// h stored in FRAGMENT ORDER: element (col c, batch b) at short idx
//   ((c>>5)*64 + ((c>>3)&3)*16 + b)*8 + (c&7)            [2048 shorts per tile]
//  -> B-frag read = b128 at 16B*(kt*64+lane): lane-contiguous, conflict-free
//  -> hnew write = b64 at ((wv>>1)*64 + ((wv&1)*2+(quad>>1))*16 + l16)*8 + (quad&1)*4:
//     dword-banks 4*(l16&7)+2*(quad&1) -> exactly 4 dwords/bank = HW minimum.
// (Round-8 bug: tile declared 1024 shorts, half the needed 2048 -> parity buffers
//  overlapped -> recurrence read mixed h(t)/h(t-1). Fixed: [2][2][2048].)
// Two groups interleaved in one instruction stream: group B's reads/MFMA/exp issue
// while group A's latencies drain. One lgkm-only barrier per step (no vmcnt drain:
// xg prefetch depth 2 + yseq stores stay in flight).
__global__ __launch_bounds__(512, 1) void k_gru(const bf16* __restrict__ xg_f,
        const bf16* __restrict__ xg_b, const float* __restrict__ wh_f,
        const float* __restrict__ wh_b, const float* __restrict__ b_f,
        const float* __restrict__ b_b, bf16* __restrict__ yseq,
        float* __restrict__ hout)
{
    const int dir   = blockIdx.y;
    const int bbase = blockIdx.x * 32;
    const bf16* xg  = dir ? xg_b : xg_f;            // [B*T, 3U]
    const float* wh = dir ? wh_b : wh_f;            // [U, 3U]
    const float* bh = (dir ? b_b : b_f) + G3;       // b[1]
    const int tid  = threadIdx.x;
    const int lane = tid & 63;
    const int wv   = tid >> 6;       // 0..7
    const int l16  = lane & 15;
    const int quad = lane >> 4;
    const int cb   = wv*16 + quad*4; // this lane's 4 gate cols

    // W^T A-frags, register-resident: A[m=wv*16+l16][k=kt*32+quad*8+j] per gate
    short8 wfrag[3][4];
    #pragma unroll
    for (int g = 0; g < 3; ++g)
        #pragma unroll
        for (int kt = 0; kt < 4; ++kt)
            #pragma unroll
            for (int j = 0; j < 8; ++j)
                reinterpret_cast<bf16*>(&wfrag[g][kt])[j] = __float2bfloat16(
                    wh[(size_t)(kt*32 + quad*8 + j)*G3 + g*U + wv*16 + l16]);

    float bz[4], br_[4], bn_[4];
    #pragma unroll
    for (int r = 0; r < 4; ++r) {
        bz[r]  = bh[      cb + r];
        br_[r] = bh[U   + cb + r];
        bn_[r] = bh[2*U + cb + r];
    }

    // write index (shorts) for this lane's b64 hnew store (same for both groups)
    const int wr_idx = ((wv>>1)*64 + ((wv&1)*2 + (quad>>1))*16 + l16)*8 + (quad&1)*4;

    __shared__ __align__(16) short hbuf[2][2][2048];   // [group][parity][frag order]
    for (int i = tid; i < 2*2*2048; i += 512) (&hbuf[0][0][0])[i] = 0;
    __syncthreads();

    float hprev[2][4] = {{0.f,0.f,0.f,0.f},{0.f,0.f,0.f,0.f}};

    // depth-2 xg prefetch, both groups (statically indexed via unroll-2 body)
    ushort4_t xs[2][2][3];   // [slot u][group][gate]
    #pragma unroll
    for (int s = 0; s < 2; ++s) {
        const int tt = dir ? (T-1-s) : s;
        #pragma unroll
        for (int gp = 0; gp < 2; ++gp) {
            const size_t ro = ((size_t)(bbase + gp*16 + l16)*T + tt)*G3;
            xs[s][gp][0] = *reinterpret_cast<const ushort4_t*>(&xg[ro +       cb]);
            xs[s][gp][1] = *reinterpret_cast<const ushort4_t*>(&xg[ro + U   + cb]);
            xs[s][gp][2] = *reinterpret_cast<const ushort4_t*>(&xg[ro + 2*U + cb]);
        }
    }

    for (int step2 = 0; step2 < T; step2 += 2) {
        #pragma unroll
        for (int u = 0; u < 2; ++u) {
            const int step = step2 + u;
            const int t = dir ? (T-1-step) : step;
            // B-frags for both groups: conflict-free b128 reads
            short8 hfrag[2][4];
            #pragma unroll
            for (int gp = 0; gp < 2; ++gp)
                #pragma unroll
                for (int kt = 0; kt < 4; ++kt)
                    hfrag[gp][kt] = *reinterpret_cast<const short8*>(
                        &hbuf[gp][u][(kt*64 + lane)*8]);
            floatx4 az[2], ar[2], an[2];
            #pragma unroll
            for (int gp = 0; gp < 2; ++gp)
                #pragma unroll
                for (int r = 0; r < 4; ++r) {
                    az[gp][r] = bz[r]; ar[gp][r] = br_[r]; an[gp][r] = bn_[r];
                }
            #pragma unroll
            for (int kt = 0; kt < 4; ++kt)
                #pragma unroll
                for (int gp = 0; gp < 2; ++gp) {
                    az[gp] = __builtin_amdgcn_mfma_f32_16x16x32_bf16(wfrag[0][kt], hfrag[gp][kt], az[gp], 0, 0, 0);
                    ar[gp] = __builtin_amdgcn_mfma_f32_16x16x32_bf16(wfrag[1][kt], hfrag[gp][kt], ar[gp], 0, 0, 0);
                    an[gp] = __builtin_amdgcn_mfma_f32_16x16x32_bf16(wfrag[2][kt], hfrag[gp][kt], an[gp], 0, 0, 0);
                }
            // consume this step's xg (loaded 2 steps ago)
            float xzv[2][4], xrv[2][4], xnv[2][4];
            #pragma unroll
            for (int gp = 0; gp < 2; ++gp)
                #pragma unroll
                for (int r = 0; r < 4; ++r) {
                    xzv[gp][r] = bfbits2f(xs[u][gp][0][r]);
                    xrv[gp][r] = bfbits2f(xs[u][gp][1][r]);
                    xnv[gp][r] = bfbits2f(xs[u][gp][2][r]);
                }
            // prefetch t+2 into slot u (clamped at tail; harmless duplicate)
            {
                const int sn = (step + 2 < T) ? step + 2 : step;
                const int tn = dir ? (T-1-sn) : sn;
                #pragma unroll
                for (int gp = 0; gp < 2; ++gp) {
                    const size_t ro = ((size_t)(bbase + gp*16 + l16)*T + tn)*G3;
                    xs[u][gp][0] = *reinterpret_cast<const ushort4_t*>(&xg[ro +       cb]);
                    xs[u][gp][1] = *reinterpret_cast<const ushort4_t*>(&xg[ro + U   + cb]);
                    xs[u][gp][2] = *reinterpret_cast<const ushort4_t*>(&xg[ro + 2*U + cb]);
                }
            }
            // gates + state update, both groups
            #pragma unroll
            for (int gp = 0; gp < 2; ++gp) {
                ushort4_t hpk;
                #pragma unroll
                for (int r = 0; r < 4; ++r) {
                    const float z  = sigmoidf_(xzv[gp][r] + az[gp][r]);
                    const float rr = sigmoidf_(xrv[gp][r] + ar[gp][r]);
                    const float n  = tanhf_(xnv[gp][r] + rr*an[gp][r]);
                    const float hnew = z*hprev[gp][r] + (1.0f - z)*n;
                    hprev[gp][r] = hnew;
                    bf16 hb = __float2bfloat16(hnew);
                    hpk[r] = *reinterpret_cast<unsigned short*>(&hb);
                }
                // conflict-free b64 write into next-parity buffer
                *reinterpret_cast<ushort4_t*>(&hbuf[gp][u^1][wr_idx]) = hpk;
                if (yseq)
                    *reinterpret_cast<ushort4_t*>(
                        &yseq[((size_t)(bbase + gp*16 + l16)*T + t)*M2 + dir*U + cb]) = hpk;
            }
            // LDS-only barrier: wait lgkmcnt(0), leave vmcnt in flight
            asm volatile("" ::: "memory");
            __builtin_amdgcn_s_waitcnt(0xC07F);
            __builtin_amdgcn_s_barrier();
            asm volatile("" ::: "memory");
        }
    }
    if (hout) {
        #pragma unroll
        for (int gp = 0; gp < 2; ++gp) {
            float4 hv = make_float4(hprev[gp][0], hprev[gp][1], hprev[gp][2], hprev[gp][3]);
            *reinterpret_cast<float4*>(
                &hout[(size_t)(bbase + gp*16 + l16)*M2 + dir*U + cb]) = hv;
        }
    }
}

// ---------------- MFMA flash attention ----------------
// Q,K,O: [B*T, HD] bf16 (head h at col h*KD). VT: [HD, B*T] bf16 (transposed V).
__global__ __launch_bounds__(256) void k_attn(const bf16* __restrict__ Q,
        const bf16* __restrict__ Kp, const bf16* __restrict__ VT,
        bf16* __restrict__ O)
{
    __shared__ short k_s[64*136];    // 17408 B
    __shared__ short vt_s[128*72];   // 18432 B
    __shared__ short p_s[64*72];     //  9216 B
    const int qt = blockIdx.x;       // 0..7
    const int b  = blockIdx.y;
    const int h  = blockIdx.z;
    const int tid  = threadIdx.x;
    const int lane = tid & 63;
    const int wv   = tid >> 6;
    const int l16  = lane & 15;
    const int quad = lane >> 4;

    short8 qfrag[4];
    {
        const size_t qoff = (size_t)(b*T + qt*64 + wv*16 + l16)*HD + h*KD + quad*8;
        #pragma unroll
        for (int kt = 0; kt < 4; ++kt)
            qfrag[kt] = *reinterpret_cast<const short8*>(&Q[qoff + kt*32]);
    }

    floatx4 Oa[8];
    #pragma unroll
    for (int nf = 0; nf < 8; ++nf) Oa[nf] = (floatx4)0.0f;
    float mrun = -1e30f, lrun = 0.0f;

    for (int kg = 0; kg < 8; ++kg) {
        __syncthreads();
        #pragma unroll
        for (int it = 0; it < 4; ++it) {
            const int linear = it*256 + tid;
            const int key = linear >> 4;
            const int dc  = linear & 15;
            const float4 v = *reinterpret_cast<const float4*>(
                &Kp[(size_t)(b*T + kg*64 + key)*HD + h*KD + dc*8]);
            *reinterpret_cast<float4*>(&k_s[key*136 + dc*8]) = v;
        }
        #pragma unroll
        for (int it = 0; it < 4; ++it) {
            const int linear = it*256 + tid;
            const int d  = linear >> 3;
            const int kc = linear & 7;
            const float4 v = *reinterpret_cast<const float4*>(
                &VT[(size_t)(h*KD + d)*BT + b*T + kg*64 + kc*8]);
            *reinterpret_cast<float4*>(&vt_s[d*72 + kc*8]) = v;
        }
        __syncthreads();
        floatx4 s[4];
        #pragma unroll
        for (int kb = 0; kb < 4; ++kb) s[kb] = (floatx4)0.0f;
        #pragma unroll
        for (int kt = 0; kt < 4; ++kt) {
            #pragma unroll
            for (int kb = 0; kb < 4; ++kb) {
                const short8 af = *reinterpret_cast<const short8*>(
                    &k_s[(kb*16 + l16)*136 + kt*32 + quad*8]);
                s[kb] = __builtin_amdgcn_mfma_f32_16x16x32_bf16(af, qfrag[kt], s[kb], 0, 0, 0);
            }
        }
        float kmax = -1e30f;
        #pragma unroll
        for (int kb = 0; kb < 4; ++kb)
            #pragma unroll
            for (int r = 0; r < 4; ++r) {
                s[kb][r] *= 0.08838834764831845f;
                kmax = fmaxf(kmax, s[kb][r]);
            }
        kmax = fmaxf(kmax, __shfl_xor(kmax, 16));
        kmax = fmaxf(kmax, __shfl_xor(kmax, 32));
        const float mnew  = fmaxf(mrun, kmax);
        const float alpha = __expf(mrun - mnew);
        float psum = 0.0f;
        #pragma unroll
        for (int kb = 0; kb < 4; ++kb)
            #pragma unroll
            for (int r = 0; r < 4; ++r) {
                const float p = __expf(s[kb][r] - mnew);
                s[kb][r] = p;
                psum += p;
            }
        psum += __shfl_xor(psum, 16);
        psum += __shfl_xor(psum, 32);
        lrun = lrun*alpha + psum;
        mrun = mnew;
        #pragma unroll
        for (int r = 0; r < 4; ++r) {
            const float ar = __shfl(alpha, quad*4 + r);
            #pragma unroll
            for (int nf = 0; nf < 8; ++nf) Oa[nf][r] *= ar;
        }
        bf16* pb = reinterpret_cast<bf16*>(p_s);
        #pragma unroll
        for (int kb = 0; kb < 4; ++kb)
            #pragma unroll
            for (int r = 0; r < 4; ++r)
                pb[(wv*16 + l16)*72 + kb*16 + quad*4 + r] = __float2bfloat16(s[kb][r]);
        #pragma unroll
        for (int kt2 = 0; kt2 < 2; ++kt2) {
            const short8 pf = *reinterpret_cast<const short8*>(
                &p_s[(wv*16 + l16)*72 + kt2*32 + quad*8]);
            #pragma unroll
            for (int nf = 0; nf < 8; ++nf) {
                const short8 vf = *reinterpret_cast<const short8*>(
                    &vt_s[(nf*16 + l16)*72 + kt2*32 + quad*8]);
                Oa[nf] = __builtin_amdgcn_mfma_f32_16x16x32_bf16(pf, vf, Oa[nf], 0, 0, 0);
            }
        }
    }
    float linv[4];
    #pragma unroll
    for (int r = 0; r < 4; ++r) linv[r] = 1.0f / __shfl(lrun, quad*4 + r);
    #pragma unroll
    for (int nf = 0; nf < 8; ++nf)
        #pragma unroll
        for (int r = 0; r < 4; ++r) {
            const size_t row = (size_t)(b*T + qt*64 + wv*16 + quad*4 + r);
            O[row*HD + h*KD + nf*16 + l16] = __float2bfloat16(Oa[nf][r] * linv[r]);
        }
}

// ---------------- dense head ----------------
__global__ void k_dense(const float* __restrict__ h2, const float* __restrict__ dw,
                        const float* __restrict__ db, float* __restrict__ out)
{
    const int b = threadIdx.x;
    float acc = db[0];
    for (int mm = 0; mm < M2; ++mm) acc += h2[b*M2 + mm] * dw[mm];
    out[b] = acc;
}

extern "C" void kernel_launch(void* const* d_in, const int* in_sizes, int n_in,
                              void* d_out, int out_size, void* d_ws, size_t ws_size,
                              hipStream_t stream)
{
    const float* inputs  = (const float*)d_in[0];
    const float* conv_w  = (const float*)d_in[1];
    const float* conv_b  = (const float*)d_in[2];
    const float* bn_g    = (const float*)d_in[3];
    const float* bn_b    = (const float*)d_in[4];
    const float* bn_m    = (const float*)d_in[5];
    const float* bn_v    = (const float*)d_in[6];
    const float* g1f_wx  = (const float*)d_in[7];
    const float* g1f_wh  = (const float*)d_in[8];
    const float* g1f_b   = (const float*)d_in[9];
    const float* g1b_wx  = (const float*)d_in[10];
    const float* g1b_wh  = (const float*)d_in[11];
    const float* g1b_b   = (const float*)d_in[12];
    const float* wq      = (const float*)d_in[13];
    const float* bq      = (const float*)d_in[14];
    const float* wk      = (const float*)d_in[15];
    const float* bk      = (const float*)d_in[16];
    const float* wv_     = (const float*)d_in[17];
    const float* bv      = (const float*)d_in[18];
    const float* wo      = (const float*)d_in[19];
    const float* bo      = (const float*)d_in[20];
    const float* g2f_wx  = (const float*)d_in[21];
    const float* g2f_wh  = (const float*)d_in[22];
    const float* g2f_b   = (const float*)d_in[23];
    const float* g2b_wx  = (const float*)d_in[24];
    const float* g2b_wh  = (const float*)d_in[25];
    const float* g2b_b   = (const float*)d_in[26];
    const float* dense_w = (const float*)d_in[27];
    const float* dense_b = (const float*)d_in[28];
    float* out = (float*)d_out;
    (void)in_sizes; (void)n_in; (void)out_size; (void)ws_size;

    // ---- workspace (float-slot offsets into 128 MiB = 33,554,432 fslots) ----
    float* ws = (float*)d_ws;
    bf16* wb = (bf16*)ws;
    bf16* g1fT = wb;            // [384,64]
    bf16* g1bT = wb + 24576;
    bf16* wqT  = wb + 49152;    // [512,256]
    bf16* wkT  = wb + 180224;
    bf16* wvT  = wb + 311296;   // [512,256] -> GEMM-A for V^T
    bf16* woT  = wb + 442368;   // [256,512]
    bf16* g2fT = wb + 573440;   // [384,256]
    bf16* g2bT = wb + 671744;   // ends 770048 < 786432

    bf16*  x1h  = (bf16*)(ws + 393216);     // [B*T,64]
    bf16*  xg1f = (bf16*)(ws + 1441792);    // [B*T,384] bf16
    bf16*  xg1b = (bf16*)(ws + 7733248);    // [B*T,384] bf16
    bf16*  y1h  = (bf16*)(ws + 26607616);   // [B*T,256]
    bf16*  qh   = (bf16*)(ws + 393216);     // [B*T,512]
    bf16*  kh   = (bf16*)(ws + 8781824);    // [B*T,512]
    bf16*  vtg  = (bf16*)(ws + 17170432);   // [512, B*T]
    bf16*  Oh   = qh;                       // attention output in-place
    bf16*  x2h  = (bf16*)(ws + 17170432);   // [B*T,256] (over dead vtg)
    bf16*  xg2f = (bf16*)(ws + 393216);     // [B*T,384]
    bf16*  xg2b = (bf16*)(ws + 6684672);
    float* h2   = ws + 12976128;            // [B,256]

    // 0. weight casts
    k_wcast<<<(64*384+255)/256, 256, 0, stream>>>(g1f_wx, g1fT, 64, 384);
    k_wcast<<<(64*384+255)/256, 256, 0, stream>>>(g1b_wx, g1bT, 64, 384);
    k_wcast<<<(256*512+255)/256, 256, 0, stream>>>(wq,  wqT, 256, 512);
    k_wcast<<<(256*512+255)/256, 256, 0, stream>>>(wk,  wkT, 256, 512);
    k_wcast<<<(256*512+255)/256, 256, 0, stream>>>(wv_, wvT, 256, 512);
    k_wcast<<<(512*256+255)/256, 256, 0, stream>>>(wo,  woT, 512, 256);
    k_wcast<<<(256*384+255)/256, 256, 0, stream>>>(g2f_wx, g2fT, 256, 384);
    k_wcast<<<(256*384+255)/256, 256, 0, stream>>>(g2b_wx, g2bT, 256, 384);

    // 1. conv + BN + ReLU -> x1h
    k_conv<<<dim3(T/16, B), 256, 0, stream>>>(inputs, conv_w, conv_b,
                                              bn_g, bn_b, bn_m, bn_v, x1h);
    // 2. GRU1 input gates (bf16)
    k_gemm<<<dim3(3, 256), 256, 0, stream>>>(x1h, g1fT, g1f_b, nullptr, nullptr, xg1f, 64, G3, 0);
    k_gemm<<<dim3(3, 256), 256, 0, stream>>>(x1h, g1bT, g1b_b, nullptr, nullptr, xg1b, 64, G3, 0);
    // 3. GRU1 scan -> y1h  (2 groups/block, grid 2x2)
    k_gru<<<dim3(2, 2), 512, 0, stream>>>(xg1f, xg1b, g1f_wh, g1b_wh,
                                          g1f_b, g1b_b, y1h, nullptr);
    // 4. Q,K projections; V as transposed GEMM
    k_gemm<<<dim3(4, 256), 256, 0, stream>>>(y1h, wqT, bq, nullptr, nullptr, qh, 256, HD, 0);
    k_gemm<<<dim3(4, 256), 256, 0, stream>>>(y1h, wkT, bk, nullptr, nullptr, kh, 256, HD, 0);
    k_gemm<<<dim3(BT/128, 4), 256, 0, stream>>>(wvT, y1h, bv, nullptr, nullptr, vtg, 256, BT, 1);
    // 5. MFMA flash attention, O in-place over Q
    k_attn<<<dim3(T/64, B, NH), 256, 0, stream>>>(qh, kh, vtg, Oh);
    // 6. output projection + bias + residual(y1h) -> x2h
    k_gemm<<<dim3(2, 256), 256, 0, stream>>>(Oh, woT, bo, y1h, nullptr, x2h, HD, M2, 0);
    // 7. GRU2 input gates (bf16)
    k_gemm<<<dim3(3, 256), 256, 0, stream>>>(x2h, g2fT, g2f_b, nullptr, nullptr, xg2f, 256, G3, 0);
    k_gemm<<<dim3(3, 256), 256, 0, stream>>>(x2h, g2bT, g2b_b, nullptr, nullptr, xg2b, 256, G3, 0);
    // 8. GRU2 scan -> h2
    k_gru<<<dim3(2, 2), 512, 0, stream>>>(xg2f, xg2b, g2f_wh, g2b_wh,
                                          g2f_b, g2b_b, nullptr, h2);
    // 9. dense head
    k_dense<<<1, 64, 0, stream>>>(h2, dense_w, dense_b, out);
}

// Round 10
// 1607.797 us; speedup vs baseline: 1.6553x; 1.6553x over previous
//
#include <hip/hip_runtime.h>
#include <hip/hip_bf16.h>

#define B   64
#define T   512
#define DIN 64
#define F   64
#define U   128
#define G3  384     // 3U
#define M2  256     // 2U
#define NH  4
#define KD  128
#define HD  512     // NH*KD
#define BT  (B*T)   // 32768

typedef __attribute__((ext_vector_type(8))) short short8;
typedef __attribute__((ext_vector_type(4))) float floatx4;
typedef __attribute__((ext_vector_type(4))) unsigned short ushort4_t;
typedef __hip_bfloat16 bf16;

// ---------------- weight transpose + cast: dst[n][k] = (bf16)src[k][n] ----------------
__global__ __launch_bounds__(256) void k_wcast(const float* __restrict__ src,
        bf16* __restrict__ dst, int K, int N)
{
    const int i = blockIdx.x*256 + threadIdx.x;
    if (i < K*N) {
        const int k = i / N, n = i - k*N;
        dst[n*K + k] = __float2bfloat16(src[i]);
    }
}

// ---------------- conv1d(same,k=3) + BN(inference) + ReLU -> bf16 ----------------
__global__ __launch_bounds__(256) void k_conv(const float* __restrict__ in,
        const float* __restrict__ cw, const float* __restrict__ cb,
        const float* __restrict__ gamma, const float* __restrict__ beta,
        const float* __restrict__ mean, const float* __restrict__ var,
        bf16* __restrict__ x1h)
{
    __shared__ float w_s[3*64*64];   // 48 KB
    __shared__ float in_s[18*64];
    const int b  = blockIdx.y;
    const int t0 = blockIdx.x * 16;
    const int tid = threadIdx.x;
    for (int idx = tid; idx < 3*64*64; idx += 256) w_s[idx] = cw[idx];
    for (int idx = tid; idx < 18*64; idx += 256) {
        int row = idx >> 6;
        int d   = idx & 63;
        int t   = t0 - 1 + row;
        in_s[idx] = (t >= 0 && t < T) ? in[((size_t)b*T + t)*DIN + d] : 0.0f;
    }
    __syncthreads();
    const int f  = tid & 63;
    const int tl = tid >> 6;   // 0..3
    const float scale = gamma[f] * rsqrtf(var[f] + 1e-3f);
    const float shift = beta[f] - mean[f] * scale;
    const float bias  = cb[f];
    for (int q = 0; q < 4; ++q) {
        const int tt = tl*4 + q;   // 0..15
        float acc = bias;
        for (int tap = 0; tap < 3; ++tap) {
            const float* irow = &in_s[(tt + tap)*64];
            const float* wrow = &w_s[tap*64*64 + f];
            #pragma unroll 16
            for (int d = 0; d < 64; ++d) acc += irow[d] * wrow[d*64];
        }
        float v = acc * scale + shift;
        x1h[((size_t)b*T + t0 + tt)*F + f] = __float2bfloat16(fmaxf(v, 0.0f));
    }
}

// ------------- MFMA bf16 GEMM: C[R,N] = A[R,K] @ Bt[N,K]^T + bias (+resid) -------------
__global__ __launch_bounds__(256) void k_gemm(const bf16* __restrict__ A,
        const bf16* __restrict__ Bt, const float* __restrict__ bias,
        const bf16* __restrict__ resid, float* __restrict__ outF,
        bf16* __restrict__ outH, int K, int N, int biasRow)
{
    __shared__ short As[128*32];   // 8 KB
    __shared__ short Bs[128*32];   // 8 KB
    const int nbase = blockIdx.x * 128;
    const int rbase = blockIdx.y * 128;
    const int tid  = threadIdx.x;
    const int lane = tid & 63;
    const int wv   = tid >> 6;
    const int wm   = wv & 1;        // row half
    const int wn   = wv >> 1;       // col half
    const int l16  = lane & 15;
    const int quad = lane >> 4;

    floatx4 acc[4][4];
    #pragma unroll
    for (int i = 0; i < 4; ++i)
        #pragma unroll
        for (int j = 0; j < 4; ++j) acc[i][j] = (floatx4)0.0f;

    const int row  = tid >> 1;           // staging: 2 threads per tile-row
    const int koff = (tid & 1) * 16;     // 16 bf16 = 32 B per thread
    const int nK = K >> 5;
    for (int kt = 0; kt < nK; ++kt) {
        if (kt) __syncthreads();
        {
            const float4* ga = reinterpret_cast<const float4*>(
                &A[(size_t)(rbase + row)*K + kt*32 + koff]);
            const float4 a0 = ga[0], a1 = ga[1];
            const float4* gb = reinterpret_cast<const float4*>(
                &Bt[(size_t)(nbase + row)*K + kt*32 + koff]);
            const float4 b0 = gb[0], b1 = gb[1];
            float4* la = reinterpret_cast<float4*>(&As[row*32 + koff]);
            la[0] = a0; la[1] = a1;
            float4* lb = reinterpret_cast<float4*>(&Bs[row*32 + koff]);
            lb[0] = b0; lb[1] = b1;
        }
        __syncthreads();
        short8 af[4], bf[4];
        #pragma unroll
        for (int i = 0; i < 4; ++i)
            af[i] = *reinterpret_cast<const short8*>(&As[(wm*64 + i*16 + l16)*32 + quad*8]);
        #pragma unroll
        for (int j = 0; j < 4; ++j)
            bf[j] = *reinterpret_cast<const short8*>(&Bs[(wn*64 + j*16 + l16)*32 + quad*8]);
        #pragma unroll
        for (int i = 0; i < 4; ++i)
            #pragma unroll
            for (int j = 0; j < 4; ++j)
                acc[i][j] = __builtin_amdgcn_mfma_f32_16x16x32_bf16(af[i], bf[j], acc[i][j], 0, 0, 0);
    }

    #pragma unroll
    for (int j = 0; j < 4; ++j) {
        const int gcol = nbase + wn*64 + j*16 + l16;
        const float bj = biasRow ? 0.0f : bias[gcol];
        #pragma unroll
        for (int i = 0; i < 4; ++i) {
            #pragma unroll
            for (int r = 0; r < 4; ++r) {
                const int grow = rbase + wm*64 + i*16 + quad*4 + r;
                const size_t off = (size_t)grow*N + gcol;
                float v = acc[i][j][r] + (biasRow ? bias[grow] : bj);
                if (resid) v += __bfloat162float(resid[off]);
                if (outF) outF[off] = v;
                if (outH) outH[off] = __float2bfloat16(v);
            }
        }
    }
}

// ---------------- MFMA-batched GRU scan (transposed, frag-order, 1 chain/CU) ----------------
__device__ __forceinline__ float sigmoidf_(float x){ return 1.0f/(1.0f + __expf(-x)); }
__device__ __forceinline__ float tanhf_(float x){ return 2.0f/(1.0f + __expf(-2.0f*x)) - 1.0f; }
__device__ __forceinline__ float bfbits2f(unsigned short u){
    return __uint_as_float(((unsigned)u) << 16);
}

// Block = 16 batches x 1 dir; grid (4,2) = 8 blocks -> one chain per CU (r9 showed
// the step is per-CU pipe-bound: 2 chains/CU doubled step time). 512 thr = 8 waves.
// hg^T = W^T(A,regs) . H^T(B,LDS). Wave wv owns gate cols wv*16..+15 (x3 gates).
// h stored in FRAGMENT ORDER: element (col c, batch b) at short idx
//   ((c>>5)*64 + ((c>>3)&3)*16 + b)*8 + (c&7)            [2048 shorts per tile]
//  -> B-frag read = b128 at 16B*(kt*64+lane): lane-contiguous, conflict-free
//  -> hnew write = b64 at ((wv>>1)*64 + ((wv&1)*2+(quad>>1))*16 + l16)*8 + (quad&1)*4:
//     dword-banks 4*(l16&7)+2*(quad&1) -> exactly 4 dwords/bank = HW minimum.
// One lgkm-only barrier per step (no vmcnt drain: depth-2 xg prefetch + yseq
// stores stay in flight across steps).
__global__ __launch_bounds__(512, 1) void k_gru(const bf16* __restrict__ xg_f,
        const bf16* __restrict__ xg_b, const float* __restrict__ wh_f,
        const float* __restrict__ wh_b, const float* __restrict__ b_f,
        const float* __restrict__ b_b, bf16* __restrict__ yseq,
        float* __restrict__ hout)
{
    const int dir   = blockIdx.y;
    const int bbase = blockIdx.x * 16;
    const bf16* xg  = dir ? xg_b : xg_f;            // [B*T, 3U]
    const float* wh = dir ? wh_b : wh_f;            // [U, 3U]
    const float* bh = (dir ? b_b : b_f) + G3;       // b[1]
    const int tid  = threadIdx.x;
    const int lane = tid & 63;
    const int wv   = tid >> 6;       // 0..7
    const int l16  = lane & 15;
    const int quad = lane >> 4;
    const int cb   = wv*16 + quad*4; // this lane's 4 gate cols
    const int brow = bbase + l16;    // this lane's batch

    // W^T A-frags, register-resident: A[m=wv*16+l16][k=kt*32+quad*8+j] per gate
    short8 wfrag[3][4];
    #pragma unroll
    for (int g = 0; g < 3; ++g)
        #pragma unroll
        for (int kt = 0; kt < 4; ++kt)
            #pragma unroll
            for (int j = 0; j < 8; ++j)
                reinterpret_cast<bf16*>(&wfrag[g][kt])[j] = __float2bfloat16(
                    wh[(size_t)(kt*32 + quad*8 + j)*G3 + g*U + wv*16 + l16]);

    float bz[4], br_[4], bn_[4];
    #pragma unroll
    for (int r = 0; r < 4; ++r) {
        bz[r]  = bh[      cb + r];
        br_[r] = bh[U   + cb + r];
        bn_[r] = bh[2*U + cb + r];
    }

    // write index (shorts) for this lane's b64 hnew store
    const int wr_idx = ((wv>>1)*64 + ((wv&1)*2 + (quad>>1))*16 + l16)*8 + (quad&1)*4;

    __shared__ __align__(16) short hbuf[2][2048];   // [parity][frag order]
    for (int i = tid; i < 2*2048; i += 512) (&hbuf[0][0])[i] = 0;
    __syncthreads();

    float hprev[4] = {0.f, 0.f, 0.f, 0.f};

    // depth-2 xg prefetch (statically indexed via unroll-2 body)
    ushort4_t xs[2][3];   // [slot u][gate]
    #pragma unroll
    for (int s = 0; s < 2; ++s) {
        const int tt = dir ? (T-1-s) : s;
        const size_t ro = ((size_t)brow*T + tt)*G3;
        xs[s][0] = *reinterpret_cast<const ushort4_t*>(&xg[ro +       cb]);
        xs[s][1] = *reinterpret_cast<const ushort4_t*>(&xg[ro + U   + cb]);
        xs[s][2] = *reinterpret_cast<const ushort4_t*>(&xg[ro + 2*U + cb]);
    }

    for (int step2 = 0; step2 < T; step2 += 2) {
        #pragma unroll
        for (int u = 0; u < 2; ++u) {
            const int step = step2 + u;
            const int t = dir ? (T-1-step) : step;
            // B-frags: conflict-free lane-contiguous b128 reads
            short8 hfrag[4];
            #pragma unroll
            for (int kt = 0; kt < 4; ++kt)
                hfrag[kt] = *reinterpret_cast<const short8*>(
                    &hbuf[u][(kt*64 + lane)*8]);
            floatx4 az, ar, an;
            #pragma unroll
            for (int r = 0; r < 4; ++r) { az[r]=bz[r]; ar[r]=br_[r]; an[r]=bn_[r]; }
            #pragma unroll
            for (int kt = 0; kt < 4; ++kt) {
                az = __builtin_amdgcn_mfma_f32_16x16x32_bf16(wfrag[0][kt], hfrag[kt], az, 0, 0, 0);
                ar = __builtin_amdgcn_mfma_f32_16x16x32_bf16(wfrag[1][kt], hfrag[kt], ar, 0, 0, 0);
                an = __builtin_amdgcn_mfma_f32_16x16x32_bf16(wfrag[2][kt], hfrag[kt], an, 0, 0, 0);
            }
            // consume this step's xg (loaded 2 steps ago)
            float xzv[4], xrv[4], xnv[4];
            #pragma unroll
            for (int r = 0; r < 4; ++r) {
                xzv[r] = bfbits2f(xs[u][0][r]);
                xrv[r] = bfbits2f(xs[u][1][r]);
                xnv[r] = bfbits2f(xs[u][2][r]);
            }
            // prefetch t+2 into slot u (clamped at tail; harmless duplicate)
            {
                const int sn = (step + 2 < T) ? step + 2 : step;
                const int tn = dir ? (T-1-sn) : sn;
                const size_t ro = ((size_t)brow*T + tn)*G3;
                xs[u][0] = *reinterpret_cast<const ushort4_t*>(&xg[ro +       cb]);
                xs[u][1] = *reinterpret_cast<const ushort4_t*>(&xg[ro + U   + cb]);
                xs[u][2] = *reinterpret_cast<const ushort4_t*>(&xg[ro + 2*U + cb]);
            }
            // gates + state update (batch brow, cols cb..cb+3)
            ushort4_t hpk;
            #pragma unroll
            for (int r = 0; r < 4; ++r) {
                const float z  = sigmoidf_(xzv[r] + az[r]);
                const float rr = sigmoidf_(xrv[r] + ar[r]);
                const float n  = tanhf_(xnv[r] + rr*an[r]);
                const float hnew = z*hprev[r] + (1.0f - z)*n;
                hprev[r] = hnew;
                bf16 hb = __float2bfloat16(hnew);
                hpk[r] = *reinterpret_cast<unsigned short*>(&hb);
            }
            // conflict-free b64 write into next-parity buffer
            *reinterpret_cast<ushort4_t*>(&hbuf[u^1][wr_idx]) = hpk;
            if (yseq)
                *reinterpret_cast<ushort4_t*>(
                    &yseq[((size_t)brow*T + t)*M2 + dir*U + cb]) = hpk;
            // LDS-only barrier: wait lgkmcnt(0), leave vmcnt in flight
            asm volatile("" ::: "memory");
            __builtin_amdgcn_s_waitcnt(0xC07F);
            __builtin_amdgcn_s_barrier();
            asm volatile("" ::: "memory");
        }
    }
    if (hout) {
        float4 hv = make_float4(hprev[0], hprev[1], hprev[2], hprev[3]);
        *reinterpret_cast<float4*>(&hout[(size_t)brow*M2 + dir*U + cb]) = hv;
    }
}

// ---------------- MFMA flash attention ----------------
// Q,K,O: [B*T, HD] bf16 (head h at col h*KD). VT: [HD, B*T] bf16 (transposed V).
__global__ __launch_bounds__(256) void k_attn(const bf16* __restrict__ Q,
        const bf16* __restrict__ Kp, const bf16* __restrict__ VT,
        bf16* __restrict__ O)
{
    __shared__ short k_s[64*136];    // 17408 B
    __shared__ short vt_s[128*72];   // 18432 B
    __shared__ short p_s[64*72];     //  9216 B
    const int qt = blockIdx.x;       // 0..7
    const int b  = blockIdx.y;
    const int h  = blockIdx.z;
    const int tid  = threadIdx.x;
    const int lane = tid & 63;
    const int wv   = tid >> 6;
    const int l16  = lane & 15;
    const int quad = lane >> 4;

    short8 qfrag[4];
    {
        const size_t qoff = (size_t)(b*T + qt*64 + wv*16 + l16)*HD + h*KD + quad*8;
        #pragma unroll
        for (int kt = 0; kt < 4; ++kt)
            qfrag[kt] = *reinterpret_cast<const short8*>(&Q[qoff + kt*32]);
    }

    floatx4 Oa[8];
    #pragma unroll
    for (int nf = 0; nf < 8; ++nf) Oa[nf] = (floatx4)0.0f;
    float mrun = -1e30f, lrun = 0.0f;

    for (int kg = 0; kg < 8; ++kg) {
        __syncthreads();
        #pragma unroll
        for (int it = 0; it < 4; ++it) {
            const int linear = it*256 + tid;
            const int key = linear >> 4;
            const int dc  = linear & 15;
            const float4 v = *reinterpret_cast<const float4*>(
                &Kp[(size_t)(b*T + kg*64 + key)*HD + h*KD + dc*8]);
            *reinterpret_cast<float4*>(&k_s[key*136 + dc*8]) = v;
        }
        #pragma unroll
        for (int it = 0; it < 4; ++it) {
            const int linear = it*256 + tid;
            const int d  = linear >> 3;
            const int kc = linear & 7;
            const float4 v = *reinterpret_cast<const float4*>(
                &VT[(size_t)(h*KD + d)*BT + b*T + kg*64 + kc*8]);
            *reinterpret_cast<float4*>(&vt_s[d*72 + kc*8]) = v;
        }
        __syncthreads();
        floatx4 s[4];
        #pragma unroll
        for (int kb = 0; kb < 4; ++kb) s[kb] = (floatx4)0.0f;
        #pragma unroll
        for (int kt = 0; kt < 4; ++kt) {
            #pragma unroll
            for (int kb = 0; kb < 4; ++kb) {
                const short8 af = *reinterpret_cast<const short8*>(
                    &k_s[(kb*16 + l16)*136 + kt*32 + quad*8]);
                s[kb] = __builtin_amdgcn_mfma_f32_16x16x32_bf16(af, qfrag[kt], s[kb], 0, 0, 0);
            }
        }
        float kmax = -1e30f;
        #pragma unroll
        for (int kb = 0; kb < 4; ++kb)
            #pragma unroll
            for (int r = 0; r < 4; ++r) {
                s[kb][r] *= 0.08838834764831845f;
                kmax = fmaxf(kmax, s[kb][r]);
            }
        kmax = fmaxf(kmax, __shfl_xor(kmax, 16));
        kmax = fmaxf(kmax, __shfl_xor(kmax, 32));
        const float mnew  = fmaxf(mrun, kmax);
        const float alpha = __expf(mrun - mnew);
        float psum = 0.0f;
        #pragma unroll
        for (int kb = 0; kb < 4; ++kb)
            #pragma unroll
            for (int r = 0; r < 4; ++r) {
                const float p = __expf(s[kb][r] - mnew);
                s[kb][r] = p;
                psum += p;
            }
        psum += __shfl_xor(psum, 16);
        psum += __shfl_xor(psum, 32);
        lrun = lrun*alpha + psum;
        mrun = mnew;
        #pragma unroll
        for (int r = 0; r < 4; ++r) {
            const float ar = __shfl(alpha, quad*4 + r);
            #pragma unroll
            for (int nf = 0; nf < 8; ++nf) Oa[nf][r] *= ar;
        }
        bf16* pb = reinterpret_cast<bf16*>(p_s);
        #pragma unroll
        for (int kb = 0; kb < 4; ++kb)
            #pragma unroll
            for (int r = 0; r < 4; ++r)
                pb[(wv*16 + l16)*72 + kb*16 + quad*4 + r] = __float2bfloat16(s[kb][r]);
        #pragma unroll
        for (int kt2 = 0; kt2 < 2; ++kt2) {
            const short8 pf = *reinterpret_cast<const short8*>(
                &p_s[(wv*16 + l16)*72 + kt2*32 + quad*8]);
            #pragma unroll
            for (int nf = 0; nf < 8; ++nf) {
                const short8 vf = *reinterpret_cast<const short8*>(
                    &vt_s[(nf*16 + l16)*72 + kt2*32 + quad*8]);
                Oa[nf] = __builtin_amdgcn_mfma_f32_16x16x32_bf16(pf, vf, Oa[nf], 0, 0, 0);
            }
        }
    }
    float linv[4];
    #pragma unroll
    for (int r = 0; r < 4; ++r) linv[r] = 1.0f / __shfl(lrun, quad*4 + r);
    #pragma unroll
    for (int nf = 0; nf < 8; ++nf)
        #pragma unroll
        for (int r = 0; r < 4; ++r) {
            const size_t row = (size_t)(b*T + qt*64 + wv*16 + quad*4 + r);
            O[row*HD + h*KD + nf*16 + l16] = __float2bfloat16(Oa[nf][r] * linv[r]);
        }
}

// ---------------- dense head ----------------
__global__ void k_dense(const float* __restrict__ h2, const float* __restrict__ dw,
                        const float* __restrict__ db, float* __restrict__ out)
{
    const int b = threadIdx.x;
    float acc = db[0];
    for (int mm = 0; mm < M2; ++mm) acc += h2[b*M2 + mm] * dw[mm];
    out[b] = acc;
}

extern "C" void kernel_launch(void* const* d_in, const int* in_sizes, int n_in,
                              void* d_out, int out_size, void* d_ws, size_t ws_size,
                              hipStream_t stream)
{
    const float* inputs  = (const float*)d_in[0];
    const float* conv_w  = (const float*)d_in[1];
    const float* conv_b  = (const float*)d_in[2];
    const float* bn_g    = (const float*)d_in[3];
    const float* bn_b    = (const float*)d_in[4];
    const float* bn_m    = (const float*)d_in[5];
    const float* bn_v    = (const float*)d_in[6];
    const float* g1f_wx  = (const float*)d_in[7];
    const float* g1f_wh  = (const float*)d_in[8];
    const float* g1f_b   = (const float*)d_in[9];
    const float* g1b_wx  = (const float*)d_in[10];
    const float* g1b_wh  = (const float*)d_in[11];
    const float* g1b_b   = (const float*)d_in[12];
    const float* wq      = (const float*)d_in[13];
    const float* bq      = (const float*)d_in[14];
    const float* wk      = (const float*)d_in[15];
    const float* bk      = (const float*)d_in[16];
    const float* wv_     = (const float*)d_in[17];
    const float* bv      = (const float*)d_in[18];
    const float* wo      = (const float*)d_in[19];
    const float* bo      = (const float*)d_in[20];
    const float* g2f_wx  = (const float*)d_in[21];
    const float* g2f_wh  = (const float*)d_in[22];
    const float* g2f_b   = (const float*)d_in[23];
    const float* g2b_wx  = (const float*)d_in[24];
    const float* g2b_wh  = (const float*)d_in[25];
    const float* g2b_b   = (const float*)d_in[26];
    const float* dense_w = (const float*)d_in[27];
    const float* dense_b = (const float*)d_in[28];
    float* out = (float*)d_out;
    (void)in_sizes; (void)n_in; (void)out_size; (void)ws_size;

    // ---- workspace (float-slot offsets into 128 MiB = 33,554,432 fslots) ----
    float* ws = (float*)d_ws;
    bf16* wb = (bf16*)ws;
    bf16* g1fT = wb;            // [384,64]
    bf16* g1bT = wb + 24576;
    bf16* wqT  = wb + 49152;    // [512,256]
    bf16* wkT  = wb + 180224;
    bf16* wvT  = wb + 311296;   // [512,256] -> GEMM-A for V^T
    bf16* woT  = wb + 442368;   // [256,512]
    bf16* g2fT = wb + 573440;   // [384,256]
    bf16* g2bT = wb + 671744;   // ends 770048 < 786432

    bf16*  x1h  = (bf16*)(ws + 393216);     // [B*T,64]
    bf16*  xg1f = (bf16*)(ws + 1441792);    // [B*T,384] bf16
    bf16*  xg1b = (bf16*)(ws + 7733248);    // [B*T,384] bf16
    bf16*  y1h  = (bf16*)(ws + 26607616);   // [B*T,256]
    bf16*  qh   = (bf16*)(ws + 393216);     // [B*T,512]
    bf16*  kh   = (bf16*)(ws + 8781824);    // [B*T,512]
    bf16*  vtg  = (bf16*)(ws + 17170432);   // [512, B*T]
    bf16*  Oh   = qh;                       // attention output in-place
    bf16*  x2h  = (bf16*)(ws + 17170432);   // [B*T,256] (over dead vtg)
    bf16*  xg2f = (bf16*)(ws + 393216);     // [B*T,384]
    bf16*  xg2b = (bf16*)(ws + 6684672);
    float* h2   = ws + 12976128;            // [B,256]

    // 0. weight casts
    k_wcast<<<(64*384+255)/256, 256, 0, stream>>>(g1f_wx, g1fT, 64, 384);
    k_wcast<<<(64*384+255)/256, 256, 0, stream>>>(g1b_wx, g1bT, 64, 384);
    k_wcast<<<(256*512+255)/256, 256, 0, stream>>>(wq,  wqT, 256, 512);
    k_wcast<<<(256*512+255)/256, 256, 0, stream>>>(wk,  wkT, 256, 512);
    k_wcast<<<(256*512+255)/256, 256, 0, stream>>>(wv_, wvT, 256, 512);
    k_wcast<<<(512*256+255)/256, 256, 0, stream>>>(wo,  woT, 512, 256);
    k_wcast<<<(256*384+255)/256, 256, 0, stream>>>(g2f_wx, g2fT, 256, 384);
    k_wcast<<<(256*384+255)/256, 256, 0, stream>>>(g2b_wx, g2bT, 256, 384);

    // 1. conv + BN + ReLU -> x1h
    k_conv<<<dim3(T/16, B), 256, 0, stream>>>(inputs, conv_w, conv_b,
                                              bn_g, bn_b, bn_m, bn_v, x1h);
    // 2. GRU1 input gates (bf16)
    k_gemm<<<dim3(3, 256), 256, 0, stream>>>(x1h, g1fT, g1f_b, nullptr, nullptr, xg1f, 64, G3, 0);
    k_gemm<<<dim3(3, 256), 256, 0, stream>>>(x1h, g1bT, g1b_b, nullptr, nullptr, xg1b, 64, G3, 0);
    // 3. GRU1 scan -> y1h  (1 chain per CU, grid 4x2)
    k_gru<<<dim3(4, 2), 512, 0, stream>>>(xg1f, xg1b, g1f_wh, g1b_wh,
                                          g1f_b, g1b_b, y1h, nullptr);
    // 4. Q,K projections; V as transposed GEMM
    k_gemm<<<dim3(4, 256), 256, 0, stream>>>(y1h, wqT, bq, nullptr, nullptr, qh, 256, HD, 0);
    k_gemm<<<dim3(4, 256), 256, 0, stream>>>(y1h, wkT, bk, nullptr, nullptr, kh, 256, HD, 0);
    k_gemm<<<dim3(BT/128, 4), 256, 0, stream>>>(wvT, y1h, bv, nullptr, nullptr, vtg, 256, BT, 1);
    // 5. MFMA flash attention, O in-place over Q
    k_attn<<<dim3(T/64, B, NH), 256, 0, stream>>>(qh, kh, vtg, Oh);
    // 6. output projection + bias + residual(y1h) -> x2h
    k_gemm<<<dim3(2, 256), 256, 0, stream>>>(Oh, woT, bo, y1h, nullptr, x2h, HD, M2, 0);
    // 7. GRU2 input gates (bf16)
    k_gemm<<<dim3(3, 256), 256, 0, stream>>>(x2h, g2fT, g2f_b, nullptr, nullptr, xg2f, 256, G3, 0);
    k_gemm<<<dim3(3, 256), 256, 0, stream>>>(x2h, g2bT, g2b_b, nullptr, nullptr, xg2b, 256, G3, 0);
    // 8. GRU2 scan -> h2
    k_gru<<<dim3(4, 2), 512, 0, stream>>>(xg2f, xg2b, g2f_wh, g2b_wh,
                                          g2f_b, g2b_b, nullptr, h2);
    // 9. dense head
    k_dense<<<1, 64, 0, stream>>>(h2, dense_w, dense_b, out);
}

// Round 11
// 1559.863 us; speedup vs baseline: 1.7061x; 1.0307x over previous
//
#include <hip/hip_runtime.h>
#include <hip/hip_bf16.h>

#define B   64
#define T   512
#define DIN 64
#define F   64
#define U   128
#define G3  384     // 3U
#define M2  256     // 2U
#define NH  4
#define KD  128
#define HD  512     // NH*KD
#define BT  (B*T)   // 32768

typedef __attribute__((ext_vector_type(8))) short short8;
typedef __attribute__((ext_vector_type(4))) float floatx4;
typedef __attribute__((ext_vector_type(4))) unsigned short ushort4_t;
typedef __hip_bfloat16 bf16;

// ---------------- fused weight transpose+cast: 8 segments, one launch ----------------
__device__ __forceinline__ void wcast_seg(const float* __restrict__ src,
        bf16* __restrict__ dst, int K, int N, int i)
{
    if (i < K*N) {
        const int k = i / N, n = i - k*N;
        dst[n*K + k] = __float2bfloat16(src[i]);
    }
}

__global__ __launch_bounds__(256) void k_wcast_all(
        const float* __restrict__ s0, const float* __restrict__ s1,
        const float* __restrict__ s2, const float* __restrict__ s3,
        const float* __restrict__ s4, const float* __restrict__ s5,
        const float* __restrict__ s6, const float* __restrict__ s7,
        bf16* __restrict__ wb)
{
    const int i = blockIdx.x*256 + threadIdx.x;
    switch (blockIdx.y) {
        case 0: wcast_seg(s0, wb,          64,  384, i); break;
        case 1: wcast_seg(s1, wb + 24576,  64,  384, i); break;
        case 2: wcast_seg(s2, wb + 49152,  256, 512, i); break;
        case 3: wcast_seg(s3, wb + 180224, 256, 512, i); break;
        case 4: wcast_seg(s4, wb + 311296, 256, 512, i); break;
        case 5: wcast_seg(s5, wb + 442368, 512, 256, i); break;
        case 6: wcast_seg(s6, wb + 573440, 256, 384, i); break;
        case 7: wcast_seg(s7, wb + 671744, 256, 384, i); break;
    }
}

// ---------------- conv1d(same,k=3) + BN(inference) + ReLU -> bf16 ----------------
__global__ __launch_bounds__(256) void k_conv(const float* __restrict__ in,
        const float* __restrict__ cw, const float* __restrict__ cb,
        const float* __restrict__ gamma, const float* __restrict__ beta,
        const float* __restrict__ mean, const float* __restrict__ var,
        bf16* __restrict__ x1h)
{
    __shared__ float w_s[3*64*64];   // 48 KB
    __shared__ float in_s[18*64];
    const int b  = blockIdx.y;
    const int t0 = blockIdx.x * 16;
    const int tid = threadIdx.x;
    for (int idx = tid; idx < 3*64*64; idx += 256) w_s[idx] = cw[idx];
    for (int idx = tid; idx < 18*64; idx += 256) {
        int row = idx >> 6;
        int d   = idx & 63;
        int t   = t0 - 1 + row;
        in_s[idx] = (t >= 0 && t < T) ? in[((size_t)b*T + t)*DIN + d] : 0.0f;
    }
    __syncthreads();
    const int f  = tid & 63;
    const int tl = tid >> 6;   // 0..3
    const float scale = gamma[f] * rsqrtf(var[f] + 1e-3f);
    const float shift = beta[f] - mean[f] * scale;
    const float bias  = cb[f];
    for (int q = 0; q < 4; ++q) {
        const int tt = tl*4 + q;   // 0..15
        float acc = bias;
        for (int tap = 0; tap < 3; ++tap) {
            const float* irow = &in_s[(tt + tap)*64];
            const float* wrow = &w_s[tap*64*64 + f];
            #pragma unroll 16
            for (int d = 0; d < 64; ++d) acc += irow[d] * wrow[d*64];
        }
        float v = acc * scale + shift;
        x1h[((size_t)b*T + t0 + tt)*F + f] = __float2bfloat16(fmaxf(v, 0.0f));
    }
}

// ------------- MFMA bf16 GEMM: C[R,N] = A[R,K] @ Bt[N,K]^T + bias (+resid) -------------
__global__ __launch_bounds__(256) void k_gemm(const bf16* __restrict__ A,
        const bf16* __restrict__ Bt, const float* __restrict__ bias,
        const bf16* __restrict__ resid, float* __restrict__ outF,
        bf16* __restrict__ outH, int K, int N, int biasRow)
{
    __shared__ short As[128*32];   // 8 KB
    __shared__ short Bs[128*32];   // 8 KB
    const int nbase = blockIdx.x * 128;
    const int rbase = blockIdx.y * 128;
    const int tid  = threadIdx.x;
    const int lane = tid & 63;
    const int wv   = tid >> 6;
    const int wm   = wv & 1;        // row half
    const int wn   = wv >> 1;       // col half
    const int l16  = lane & 15;
    const int quad = lane >> 4;

    floatx4 acc[4][4];
    #pragma unroll
    for (int i = 0; i < 4; ++i)
        #pragma unroll
        for (int j = 0; j < 4; ++j) acc[i][j] = (floatx4)0.0f;

    const int row  = tid >> 1;           // staging: 2 threads per tile-row
    const int koff = (tid & 1) * 16;     // 16 bf16 = 32 B per thread
    const int nK = K >> 5;
    for (int kt = 0; kt < nK; ++kt) {
        if (kt) __syncthreads();
        {
            const float4* ga = reinterpret_cast<const float4*>(
                &A[(size_t)(rbase + row)*K + kt*32 + koff]);
            const float4 a0 = ga[0], a1 = ga[1];
            const float4* gb = reinterpret_cast<const float4*>(
                &Bt[(size_t)(nbase + row)*K + kt*32 + koff]);
            const float4 b0 = gb[0], b1 = gb[1];
            float4* la = reinterpret_cast<float4*>(&As[row*32 + koff]);
            la[0] = a0; la[1] = a1;
            float4* lb = reinterpret_cast<float4*>(&Bs[row*32 + koff]);
            lb[0] = b0; lb[1] = b1;
        }
        __syncthreads();
        short8 af[4], bf[4];
        #pragma unroll
        for (int i = 0; i < 4; ++i)
            af[i] = *reinterpret_cast<const short8*>(&As[(wm*64 + i*16 + l16)*32 + quad*8]);
        #pragma unroll
        for (int j = 0; j < 4; ++j)
            bf[j] = *reinterpret_cast<const short8*>(&Bs[(wn*64 + j*16 + l16)*32 + quad*8]);
        #pragma unroll
        for (int i = 0; i < 4; ++i)
            #pragma unroll
            for (int j = 0; j < 4; ++j)
                acc[i][j] = __builtin_amdgcn_mfma_f32_16x16x32_bf16(af[i], bf[j], acc[i][j], 0, 0, 0);
    }

    #pragma unroll
    for (int j = 0; j < 4; ++j) {
        const int gcol = nbase + wn*64 + j*16 + l16;
        const float bj = biasRow ? 0.0f : bias[gcol];
        #pragma unroll
        for (int i = 0; i < 4; ++i) {
            #pragma unroll
            for (int r = 0; r < 4; ++r) {
                const int grow = rbase + wm*64 + i*16 + quad*4 + r;
                const size_t off = (size_t)grow*N + gcol;
                float v = acc[i][j][r] + (biasRow ? bias[grow] : bj);
                if (resid) v += __bfloat162float(resid[off]);
                if (outF) outF[off] = v;
                if (outH) outH[off] = __float2bfloat16(v);
            }
        }
    }
}

// ---------------- MFMA-batched GRU scan (transposed, frag-order, VALU-diet) ----------------
__device__ __forceinline__ float sigmoidf_(float x){ return 1.0f/(1.0f + __expf(-x)); }
__device__ __forceinline__ float tanhf_(float x){ return 2.0f/(1.0f + __expf(-2.0f*x)) - 1.0f; }
__device__ __forceinline__ float bfbits2f(unsigned short u){
    return __uint_as_float(((unsigned)u) << 16);
}

// Block = 16 batches x 1 dir; grid (4,2) = 8 blocks, 1 chain/CU (r9: 2 chains/CU
// doubles step time -> per-CU issue-bound). 512 thr = 8 waves.
// r10 counters: conflicts 655K->131K changed nothing; VALUBusy/activeCU ~78% ->
// step is VALU-ISSUE-bound. This round cuts per-step VALU overhead:
//  - xg/yseq addressing by pointer increment (stride +-row), 3 xg loads share one
//    pointer via +0/+256B/+512B immediate offsets; no per-step 64-bit muls
//  - no tail clamp: prefetch free-runs <=2 rows past segment (in-bounds of d_ws)
//  - recurrent bias rides as the C-operand of the first MFMA (no acc-init movs)
// h in FRAGMENT ORDER (2048 shorts/tile): B-frag read = b128 at 16B*(kt*64+lane),
// conflict-free; hnew b64 write lands 4 dwords/bank (minimum). lgkm-only barrier.
__global__ __launch_bounds__(512, 1) void k_gru(const bf16* __restrict__ xg_f,
        const bf16* __restrict__ xg_b, const float* __restrict__ wh_f,
        const float* __restrict__ wh_b, const float* __restrict__ b_f,
        const float* __restrict__ b_b, bf16* __restrict__ yseq,
        float* __restrict__ hout)
{
    const int dir   = blockIdx.y;
    const int bbase = blockIdx.x * 16;
    const bf16* xg  = dir ? xg_b : xg_f;            // [B*T, 3U]
    const float* wh = dir ? wh_b : wh_f;            // [U, 3U]
    const float* bh = (dir ? b_b : b_f) + G3;       // b[1]
    const int tid  = threadIdx.x;
    const int lane = tid & 63;
    const int wv   = tid >> 6;       // 0..7
    const int l16  = lane & 15;
    const int quad = lane >> 4;
    const int cb   = wv*16 + quad*4; // this lane's 4 gate cols
    const int brow = bbase + l16;    // this lane's batch

    // W^T A-frags, register-resident
    short8 wfrag[3][4];
    #pragma unroll
    for (int g = 0; g < 3; ++g)
        #pragma unroll
        for (int kt = 0; kt < 4; ++kt)
            #pragma unroll
            for (int j = 0; j < 8; ++j)
                reinterpret_cast<bf16*>(&wfrag[g][kt])[j] = __float2bfloat16(
                    wh[(size_t)(kt*32 + quad*8 + j)*G3 + g*U + wv*16 + l16]);

    // recurrent bias as preserved MFMA C-operands
    floatx4 bz4, br4, bn4;
    #pragma unroll
    for (int r = 0; r < 4; ++r) {
        bz4[r] = bh[      cb + r];
        br4[r] = bh[U   + cb + r];
        bn4[r] = bh[2*U + cb + r];
    }

    // write index (shorts) for this lane's b64 hnew store
    const int wr_idx = ((wv>>1)*64 + ((wv&1)*2 + (quad>>1))*16 + l16)*8 + (quad&1)*4;

    __shared__ __align__(16) short hbuf[2][2048];   // [parity][frag order]
    for (int i = tid; i < 2*2048; i += 512) (&hbuf[0][0])[i] = 0;
    __syncthreads();

    float hprev[4] = {0.f, 0.f, 0.f, 0.f};

    // pointer-increment streams (no per-step address math)
    const int t0 = dir ? T-1 : 0;
    const ptrdiff_t xstr = dir ? -(ptrdiff_t)G3 : (ptrdiff_t)G3;
    const ptrdiff_t ystr = dir ? -(ptrdiff_t)M2 : (ptrdiff_t)M2;
    const bf16* xp = xg + ((size_t)brow*T + t0)*G3 + cb;     // next row to LOAD
    bf16* yp = yseq ? (yseq + ((size_t)brow*T + t0)*M2 + dir*U + cb) : nullptr;

    // depth-2 xg prefetch (statically indexed via unroll-2 body)
    ushort4_t xs[2][3];
    #pragma unroll
    for (int s = 0; s < 2; ++s) {
        xs[s][0] = *reinterpret_cast<const ushort4_t*>(xp);
        xs[s][1] = *reinterpret_cast<const ushort4_t*>(xp + U);
        xs[s][2] = *reinterpret_cast<const ushort4_t*>(xp + 2*U);
        xp += xstr;
    }

    for (int step2 = 0; step2 < T; step2 += 2) {
        #pragma unroll
        for (int u = 0; u < 2; ++u) {
            // B-frags: conflict-free lane-contiguous b128 reads
            short8 hfrag[4];
            #pragma unroll
            for (int kt = 0; kt < 4; ++kt)
                hfrag[kt] = *reinterpret_cast<const short8*>(
                    &hbuf[u][(kt*64 + lane)*8]);
            // bias pre-loaded via C-operand of first MFMA
            floatx4 az = __builtin_amdgcn_mfma_f32_16x16x32_bf16(wfrag[0][0], hfrag[0], bz4, 0, 0, 0);
            floatx4 ar = __builtin_amdgcn_mfma_f32_16x16x32_bf16(wfrag[1][0], hfrag[0], br4, 0, 0, 0);
            floatx4 an = __builtin_amdgcn_mfma_f32_16x16x32_bf16(wfrag[2][0], hfrag[0], bn4, 0, 0, 0);
            #pragma unroll
            for (int kt = 1; kt < 4; ++kt) {
                az = __builtin_amdgcn_mfma_f32_16x16x32_bf16(wfrag[0][kt], hfrag[kt], az, 0, 0, 0);
                ar = __builtin_amdgcn_mfma_f32_16x16x32_bf16(wfrag[1][kt], hfrag[kt], ar, 0, 0, 0);
                an = __builtin_amdgcn_mfma_f32_16x16x32_bf16(wfrag[2][kt], hfrag[kt], an, 0, 0, 0);
            }
            // consume this step's xg (loaded 2 steps ago)
            float xzv[4], xrv[4], xnv[4];
            #pragma unroll
            for (int r = 0; r < 4; ++r) {
                xzv[r] = bfbits2f(xs[u][0][r]);
                xrv[r] = bfbits2f(xs[u][1][r]);
                xnv[r] = bfbits2f(xs[u][2][r]);
            }
            // refill slot u for step+2 (free-running pointer; overrun is in-bounds)
            xs[u][0] = *reinterpret_cast<const ushort4_t*>(xp);
            xs[u][1] = *reinterpret_cast<const ushort4_t*>(xp + U);
            xs[u][2] = *reinterpret_cast<const ushort4_t*>(xp + 2*U);
            xp += xstr;
            // gates + state update (batch brow, cols cb..cb+3)
            ushort4_t hpk;
            #pragma unroll
            for (int r = 0; r < 4; ++r) {
                const float z  = sigmoidf_(xzv[r] + az[r]);
                const float rr = sigmoidf_(xrv[r] + ar[r]);
                const float n  = tanhf_(xnv[r] + rr*an[r]);
                const float hnew = z*hprev[r] + (1.0f - z)*n;
                hprev[r] = hnew;
                bf16 hb = __float2bfloat16(hnew);
                hpk[r] = *reinterpret_cast<unsigned short*>(&hb);
            }
            // conflict-free b64 write into next-parity buffer
            *reinterpret_cast<ushort4_t*>(&hbuf[u^1][wr_idx]) = hpk;
            if (yp) {
                *reinterpret_cast<ushort4_t*>(yp) = hpk;
                yp += ystr;
            }
            // LDS-only barrier: wait lgkmcnt(0), leave vmcnt in flight
            asm volatile("" ::: "memory");
            __builtin_amdgcn_s_waitcnt(0xC07F);
            __builtin_amdgcn_s_barrier();
            asm volatile("" ::: "memory");
        }
    }
    if (hout) {
        float4 hv = make_float4(hprev[0], hprev[1], hprev[2], hprev[3]);
        *reinterpret_cast<float4*>(&hout[(size_t)brow*M2 + dir*U + cb]) = hv;
    }
}

// ---------------- MFMA flash attention ----------------
// Q,K,O: [B*T, HD] bf16 (head h at col h*KD). VT: [HD, B*T] bf16 (transposed V).
__global__ __launch_bounds__(256) void k_attn(const bf16* __restrict__ Q,
        const bf16* __restrict__ Kp, const bf16* __restrict__ VT,
        bf16* __restrict__ O)
{
    __shared__ short k_s[64*136];    // 17408 B
    __shared__ short vt_s[128*72];   // 18432 B
    __shared__ short p_s[64*72];     //  9216 B
    const int qt = blockIdx.x;       // 0..7
    const int b  = blockIdx.y;
    const int h  = blockIdx.z;
    const int tid  = threadIdx.x;
    const int lane = tid & 63;
    const int wv   = tid >> 6;
    const int l16  = lane & 15;
    const int quad = lane >> 4;

    short8 qfrag[4];
    {
        const size_t qoff = (size_t)(b*T + qt*64 + wv*16 + l16)*HD + h*KD + quad*8;
        #pragma unroll
        for (int kt = 0; kt < 4; ++kt)
            qfrag[kt] = *reinterpret_cast<const short8*>(&Q[qoff + kt*32]);
    }

    floatx4 Oa[8];
    #pragma unroll
    for (int nf = 0; nf < 8; ++nf) Oa[nf] = (floatx4)0.0f;
    float mrun = -1e30f, lrun = 0.0f;

    for (int kg = 0; kg < 8; ++kg) {
        __syncthreads();
        #pragma unroll
        for (int it = 0; it < 4; ++it) {
            const int linear = it*256 + tid;
            const int key = linear >> 4;
            const int dc  = linear & 15;
            const float4 v = *reinterpret_cast<const float4*>(
                &Kp[(size_t)(b*T + kg*64 + key)*HD + h*KD + dc*8]);
            *reinterpret_cast<float4*>(&k_s[key*136 + dc*8]) = v;
        }
        #pragma unroll
        for (int it = 0; it < 4; ++it) {
            const int linear = it*256 + tid;
            const int d  = linear >> 3;
            const int kc = linear & 7;
            const float4 v = *reinterpret_cast<const float4*>(
                &VT[(size_t)(h*KD + d)*BT + b*T + kg*64 + kc*8]);
            *reinterpret_cast<float4*>(&vt_s[d*72 + kc*8]) = v;
        }
        __syncthreads();
        floatx4 s[4];
        #pragma unroll
        for (int kb = 0; kb < 4; ++kb) s[kb] = (floatx4)0.0f;
        #pragma unroll
        for (int kt = 0; kt < 4; ++kt) {
            #pragma unroll
            for (int kb = 0; kb < 4; ++kb) {
                const short8 af = *reinterpret_cast<const short8*>(
                    &k_s[(kb*16 + l16)*136 + kt*32 + quad*8]);
                s[kb] = __builtin_amdgcn_mfma_f32_16x16x32_bf16(af, qfrag[kt], s[kb], 0, 0, 0);
            }
        }
        float kmax = -1e30f;
        #pragma unroll
        for (int kb = 0; kb < 4; ++kb)
            #pragma unroll
            for (int r = 0; r < 4; ++r) {
                s[kb][r] *= 0.08838834764831845f;
                kmax = fmaxf(kmax, s[kb][r]);
            }
        kmax = fmaxf(kmax, __shfl_xor(kmax, 16));
        kmax = fmaxf(kmax, __shfl_xor(kmax, 32));
        const float mnew  = fmaxf(mrun, kmax);
        const float alpha = __expf(mrun - mnew);
        float psum = 0.0f;
        #pragma unroll
        for (int kb = 0; kb < 4; ++kb)
            #pragma unroll
            for (int r = 0; r < 4; ++r) {
                const float p = __expf(s[kb][r] - mnew);
                s[kb][r] = p;
                psum += p;
            }
        psum += __shfl_xor(psum, 16);
        psum += __shfl_xor(psum, 32);
        lrun = lrun*alpha + psum;
        mrun = mnew;
        #pragma unroll
        for (int r = 0; r < 4; ++r) {
            const float ar = __shfl(alpha, quad*4 + r);
            #pragma unroll
            for (int nf = 0; nf < 8; ++nf) Oa[nf][r] *= ar;
        }
        bf16* pb = reinterpret_cast<bf16*>(p_s);
        #pragma unroll
        for (int kb = 0; kb < 4; ++kb)
            #pragma unroll
            for (int r = 0; r < 4; ++r)
                pb[(wv*16 + l16)*72 + kb*16 + quad*4 + r] = __float2bfloat16(s[kb][r]);
        #pragma unroll
        for (int kt2 = 0; kt2 < 2; ++kt2) {
            const short8 pf = *reinterpret_cast<const short8*>(
                &p_s[(wv*16 + l16)*72 + kt2*32 + quad*8]);
            #pragma unroll
            for (int nf = 0; nf < 8; ++nf) {
                const short8 vf = *reinterpret_cast<const short8*>(
                    &vt_s[(nf*16 + l16)*72 + kt2*32 + quad*8]);
                Oa[nf] = __builtin_amdgcn_mfma_f32_16x16x32_bf16(pf, vf, Oa[nf], 0, 0, 0);
            }
        }
    }
    float linv[4];
    #pragma unroll
    for (int r = 0; r < 4; ++r) linv[r] = 1.0f / __shfl(lrun, quad*4 + r);
    #pragma unroll
    for (int nf = 0; nf < 8; ++nf)
        #pragma unroll
        for (int r = 0; r < 4; ++r) {
            const size_t row = (size_t)(b*T + qt*64 + wv*16 + quad*4 + r);
            O[row*HD + h*KD + nf*16 + l16] = __float2bfloat16(Oa[nf][r] * linv[r]);
        }
}

// ---------------- dense head ----------------
__global__ void k_dense(const float* __restrict__ h2, const float* __restrict__ dw,
                        const float* __restrict__ db, float* __restrict__ out)
{
    const int b = threadIdx.x;
    float acc = db[0];
    for (int mm = 0; mm < M2; ++mm) acc += h2[b*M2 + mm] * dw[mm];
    out[b] = acc;
}

extern "C" void kernel_launch(void* const* d_in, const int* in_sizes, int n_in,
                              void* d_out, int out_size, void* d_ws, size_t ws_size,
                              hipStream_t stream)
{
    const float* inputs  = (const float*)d_in[0];
    const float* conv_w  = (const float*)d_in[1];
    const float* conv_b  = (const float*)d_in[2];
    const float* bn_g    = (const float*)d_in[3];
    const float* bn_b    = (const float*)d_in[4];
    const float* bn_m    = (const float*)d_in[5];
    const float* bn_v    = (const float*)d_in[6];
    const float* g1f_wx  = (const float*)d_in[7];
    const float* g1f_wh  = (const float*)d_in[8];
    const float* g1f_b   = (const float*)d_in[9];
    const float* g1b_wx  = (const float*)d_in[10];
    const float* g1b_wh  = (const float*)d_in[11];
    const float* g1b_b   = (const float*)d_in[12];
    const float* wq      = (const float*)d_in[13];
    const float* bq      = (const float*)d_in[14];
    const float* wk      = (const float*)d_in[15];
    const float* bk      = (const float*)d_in[16];
    const float* wv_     = (const float*)d_in[17];
    const float* bv      = (const float*)d_in[18];
    const float* wo      = (const float*)d_in[19];
    const float* bo      = (const float*)d_in[20];
    const float* g2f_wx  = (const float*)d_in[21];
    const float* g2f_wh  = (const float*)d_in[22];
    const float* g2f_b   = (const float*)d_in[23];
    const float* g2b_wx  = (const float*)d_in[24];
    const float* g2b_wh  = (const float*)d_in[25];
    const float* g2b_b   = (const float*)d_in[26];
    const float* dense_w = (const float*)d_in[27];
    const float* dense_b = (const float*)d_in[28];
    float* out = (float*)d_out;
    (void)in_sizes; (void)n_in; (void)out_size; (void)ws_size;

    // ---- workspace (float-slot offsets into 128 MiB = 33,554,432 fslots) ----
    float* ws = (float*)d_ws;
    bf16* wb = (bf16*)ws;
    bf16* g1fT = wb;            // [384,64]
    bf16* g1bT = wb + 24576;
    bf16* wqT  = wb + 49152;    // [512,256]
    bf16* wkT  = wb + 180224;
    bf16* wvT  = wb + 311296;   // [512,256] -> GEMM-A for V^T
    bf16* woT  = wb + 442368;   // [256,512]
    bf16* g2fT = wb + 573440;   // [384,256]
    bf16* g2bT = wb + 671744;   // ends 770048 < 786432

    bf16*  x1h  = (bf16*)(ws + 393216);     // [B*T,64]
    bf16*  xg1f = (bf16*)(ws + 1441792);    // [B*T,384] bf16
    bf16*  xg1b = (bf16*)(ws + 7733248);    // [B*T,384] bf16
    bf16*  y1h  = (bf16*)(ws + 26607616);   // [B*T,256]
    bf16*  qh   = (bf16*)(ws + 393216);     // [B*T,512]
    bf16*  kh   = (bf16*)(ws + 8781824);    // [B*T,512]
    bf16*  vtg  = (bf16*)(ws + 17170432);   // [512, B*T]
    bf16*  Oh   = qh;                       // attention output in-place
    bf16*  x2h  = (bf16*)(ws + 17170432);   // [B*T,256] (over dead vtg)
    bf16*  xg2f = (bf16*)(ws + 393216);     // [B*T,384]
    bf16*  xg2b = (bf16*)(ws + 6684672);
    float* h2   = ws + 12976128;            // [B,256]

    // 0. fused weight casts (one launch)
    k_wcast_all<<<dim3(512, 8), 256, 0, stream>>>(g1f_wx, g1b_wx, wq, wk, wv_,
                                                  wo, g2f_wx, g2b_wx, wb);

    // 1. conv + BN + ReLU -> x1h
    k_conv<<<dim3(T/16, B), 256, 0, stream>>>(inputs, conv_w, conv_b,
                                              bn_g, bn_b, bn_m, bn_v, x1h);
    // 2. GRU1 input gates (bf16)
    k_gemm<<<dim3(3, 256), 256, 0, stream>>>(x1h, g1fT, g1f_b, nullptr, nullptr, xg1f, 64, G3, 0);
    k_gemm<<<dim3(3, 256), 256, 0, stream>>>(x1h, g1bT, g1b_b, nullptr, nullptr, xg1b, 64, G3, 0);
    // 3. GRU1 scan -> y1h  (1 chain per CU, grid 4x2)
    k_gru<<<dim3(4, 2), 512, 0, stream>>>(xg1f, xg1b, g1f_wh, g1b_wh,
                                          g1f_b, g1b_b, y1h, nullptr);
    // 4. Q,K projections; V as transposed GEMM
    k_gemm<<<dim3(4, 256), 256, 0, stream>>>(y1h, wqT, bq, nullptr, nullptr, qh, 256, HD, 0);
    k_gemm<<<dim3(4, 256), 256, 0, stream>>>(y1h, wkT, bk, nullptr, nullptr, kh, 256, HD, 0);
    k_gemm<<<dim3(BT/128, 4), 256, 0, stream>>>(wvT, y1h, bv, nullptr, nullptr, vtg, 256, BT, 1);
    // 5. MFMA flash attention, O in-place over Q
    k_attn<<<dim3(T/64, B, NH), 256, 0, stream>>>(qh, kh, vtg, Oh);
    // 6. output projection + bias + residual(y1h) -> x2h
    k_gemm<<<dim3(2, 256), 256, 0, stream>>>(Oh, woT, bo, y1h, nullptr, x2h, HD, M2, 0);
    // 7. GRU2 input gates (bf16)
    k_gemm<<<dim3(3, 256), 256, 0, stream>>>(x2h, g2fT, g2f_b, nullptr, nullptr, xg2f, 256, G3, 0);
    k_gemm<<<dim3(3, 256), 256, 0, stream>>>(x2h, g2bT, g2b_b, nullptr, nullptr, xg2b, 256, G3, 0);
    // 8. GRU2 scan -> h2
    k_gru<<<dim3(4, 2), 512, 0, stream>>>(xg2f, xg2b, g2f_wh, g2b_wh,
                                          g2f_b, g2b_b, nullptr, h2);
    // 9. dense head
    k_dense<<<1, 64, 0, stream>>>(h2, dense_w, dense_b, out);
}